// Round 3
// baseline (545.394 us; speedup 1.0000x reference)
//
#include <hip/hip_runtime.h>
#include <hip/hip_cooperative_groups.h>

namespace cg = cooperative_groups;

// Problem shape (fixed by setup_inputs): inputs [B=32, T=4096, F=256] fp32.
constexpr int B_ = 32;
constexpr int T_ = 4096;
constexpr int F_ = 256;
constexpr int CHUNKS = 64;              // chunks along T
constexpr int L_ = T_ / CHUNKS;         // 64 steps per chunk
constexpr float EPS_ = 1e-6f;
constexpr int WAVES_PER_BLOCK = 4;      // 256-thread blocks
constexpr int NBLOCKS = (B_ * CHUNKS) / WAVES_PER_BLOCK;  // 512 blocks, 2/CU

// ---- ordered-uint encoding for float atomic min/max (handles any sign) ----
__device__ __forceinline__ unsigned f2ord(float f) {
    unsigned u = __float_as_uint(f);
    return (u & 0x80000000u) ? ~u : (u | 0x80000000u);
}
__device__ __forceinline__ float ord2f(unsigned u) {
    return (u & 0x80000000u) ? __uint_as_float(u ^ 0x80000000u)
                             : __uint_as_float(~u);
}
__device__ __forceinline__ float clamp01(float v) {
    return fminf(fmaxf(v, 0.0f), 1.0f);
}

// out_pre = (x*(EPS+ema)^-g + bias)^(1/r) - bias^(1/r)
// NOTE: phases 3 and 4 run this identical code on identical inputs, so the
// min/max found in phase 3 matches phase 4's recomputed values bitwise.
__device__ __forceinline__ float pcen_elem(float xv, float av, float g,
                                           float inv_r, float bias,
                                           float bpow) {
    const float p = __builtin_exp2f(-g * __builtin_log2f(EPS_ + av));
    const float base = fmaf(xv, p, bias);  // >= bias > 0
    return __builtin_exp2f(inv_r * __builtin_log2f(base)) - bpow;
}

__device__ __forceinline__ void ema_step(float4& a, const float4& v, float w,
                                         float d) {
    a.x = fmaf(w, v.x, d * a.x);
    a.y = fmaf(w, v.y, d * a.y);
    a.z = fmaf(w, v.z, d * a.z);
    a.w = fmaf(w, v.w, d * a.w);
}

__global__ __launch_bounds__(256) void pcen_fused(
        const float* __restrict__ x, const float* __restrict__ gain,
        const float* __restrict__ bias_p, const float* __restrict__ root,
        const float* __restrict__ smooth, float* __restrict__ out,
        float* __restrict__ E, float* __restrict__ In,
        unsigned* __restrict__ mm) {
    cg::grid_group grid = cg::this_grid();
    const int wave = threadIdx.x >> 6;
    const int lane = threadIdx.x & 63;                    // f4 group 0..63
    const int bc = blockIdx.x * WAVES_PER_BLOCK + wave;   // 0..2047 (b*64+c)

    const float w = clamp01(smooth[0]);
    const float d = 1.0f - w;
    const float g = fminf(gain[0], 1.0f);
    const float r = fmaxf(root[0], 1.0f);
    const float inv_r = 1.0f / r;
    const float bias = bias_p[0];
    const float bpow = __builtin_exp2f(inv_r * __builtin_log2f(bias));

    if (blockIdx.x == 0 && threadIdx.x == 0) {
        mm[0] = 0xFFFFFFFFu;  // ordered-min init (= +inf)
        mm[1] = 0x00000000u;  // ordered-max init (= -inf)
    }

    const float4* xp = reinterpret_cast<const float4*>(
                           x + (size_t)bc * L_ * F_) + lane;
    const size_t fidx = (size_t)bc * (F_ / 4) + lane;

    // ---- phase 1: chunk-local EMA end-state with zero seed -> E ----
    {
        float4 a = make_float4(0.f, 0.f, 0.f, 0.f);
        for (int t0 = 0; t0 < L_; t0 += 8) {
            float4 v[8];
#pragma unroll
            for (int i = 0; i < 8; ++i) v[i] = xp[(size_t)(t0 + i) * (F_ / 4)];
#pragma unroll
            for (int i = 0; i < 8; ++i) ema_step(a, v[i], w, d);
        }
        reinterpret_cast<float4*>(E)[fidx] = a;
    }
    grid.sync();

    // ---- phase 2: cross-chunk carry scan (one wave per b, 32 active) ----
    // In_0 = x[b,0,:] (reference initial state); In_c = d^L*In_{c-1} + E_{c-1}
    if (bc < B_) {
        const int b = bc;
        float dL = d;  // d^64 via repeated squaring
        dL *= dL; dL *= dL; dL *= dL; dL *= dL; dL *= dL; dL *= dL;
        float4 cur = reinterpret_cast<const float4*>(
                         x + (size_t)b * T_ * F_)[lane];
        for (int c = 0; c < CHUNKS; ++c) {
            const size_t idx = ((size_t)b * CHUNKS + c) * (F_ / 4) + lane;
            reinterpret_cast<float4*>(In)[idx] = cur;
            const float4 e = reinterpret_cast<const float4*>(E)[idx];
            cur.x = fmaf(dL, cur.x, e.x);
            cur.y = fmaf(dL, cur.y, e.y);
            cur.z = fmaf(dL, cur.z, e.z);
            cur.w = fmaf(dL, cur.w, e.w);
        }
    }
    grid.sync();

    // ---- phase 3: seeded re-scan + PCEN, global min/max only (no store) ----
    {
        float4 a = reinterpret_cast<const float4*>(In)[fidx];
        float lmin = __builtin_inff(), lmax = -__builtin_inff();
        for (int t0 = 0; t0 < L_; t0 += 8) {
            float4 v[8];
#pragma unroll
            for (int i = 0; i < 8; ++i) v[i] = xp[(size_t)(t0 + i) * (F_ / 4)];
#pragma unroll
            for (int i = 0; i < 8; ++i) {
                ema_step(a, v[i], w, d);
                float4 o;
                o.x = pcen_elem(v[i].x, a.x, g, inv_r, bias, bpow);
                o.y = pcen_elem(v[i].y, a.y, g, inv_r, bias, bpow);
                o.z = pcen_elem(v[i].z, a.z, g, inv_r, bias, bpow);
                o.w = pcen_elem(v[i].w, a.w, g, inv_r, bias, bpow);
                lmin = fminf(lmin, fminf(fminf(o.x, o.y), fminf(o.z, o.w)));
                lmax = fmaxf(lmax, fmaxf(fmaxf(o.x, o.y), fmaxf(o.z, o.w)));
            }
        }
#pragma unroll
        for (int off = 32; off > 0; off >>= 1) {
            lmin = fminf(lmin, __shfl_xor(lmin, off));
            lmax = fmaxf(lmax, __shfl_xor(lmax, off));
        }
        if (lane == 0) {
            atomicMin(&mm[0], f2ord(lmin));
            atomicMax(&mm[1], f2ord(lmax));
        }
    }
    __threadfence();
    grid.sync();

    // ---- phase 4: recompute + normalize + single out write ----
    {
        const float mn = ord2f(((volatile unsigned*)mm)[0]);
        const float mx = ord2f(((volatile unsigned*)mm)[1]);
        const float s = 2.0f / (mx - mn);
        const float off = fmaf(-mn, s, -1.0f);
        float4* op = reinterpret_cast<float4*>(
                         out + (size_t)bc * L_ * F_) + lane;
        float4 a = reinterpret_cast<const float4*>(In)[fidx];
        for (int t0 = 0; t0 < L_; t0 += 8) {
            float4 v[8];
#pragma unroll
            for (int i = 0; i < 8; ++i) v[i] = xp[(size_t)(t0 + i) * (F_ / 4)];
#pragma unroll
            for (int i = 0; i < 8; ++i) {
                ema_step(a, v[i], w, d);
                float4 o;
                o.x = fmaf(pcen_elem(v[i].x, a.x, g, inv_r, bias, bpow), s, off);
                o.y = fmaf(pcen_elem(v[i].y, a.y, g, inv_r, bias, bpow), s, off);
                o.z = fmaf(pcen_elem(v[i].z, a.z, g, inv_r, bias, bpow), s, off);
                o.w = fmaf(pcen_elem(v[i].w, a.w, g, inv_r, bias, bpow), s, off);
                op[(size_t)(t0 + i) * (F_ / 4)] = o;
            }
        }
    }
}

extern "C" void kernel_launch(void* const* d_in, const int* in_sizes, int n_in,
                              void* d_out, int out_size, void* d_ws, size_t ws_size,
                              hipStream_t stream) {
    const float* x      = (const float*)d_in[0];
    const float* gain   = (const float*)d_in[1];
    const float* bias   = (const float*)d_in[2];
    const float* root   = (const float*)d_in[3];
    const float* smooth = (const float*)d_in[4];
    float* out = (float*)d_out;

    // ws layout: E [B*CHUNKS*F] | In [B*CHUNKS*F] | mm[2]  (~4 MiB + 8 B)
    float* E  = (float*)d_ws;
    float* In = E + (size_t)B_ * CHUNKS * F_;
    unsigned* mm = (unsigned*)(In + (size_t)B_ * CHUNKS * F_);

    void* args[] = {(void*)&x, (void*)&gain, (void*)&bias, (void*)&root,
                    (void*)&smooth, (void*)&out, (void*)&E, (void*)&In,
                    (void*)&mm};
    hipLaunchCooperativeKernel((void*)pcen_fused, dim3(NBLOCKS), dim3(256),
                               args, 0, stream);
}